// Round 5
// baseline (266.376 us; speedup 1.0000x reference)
//
#include <hip/hip_runtime.h>
#include <hip/hip_bf16.h>

namespace {

constexpr int kN  = 1024;
constexpr int kU  = 64;
constexpr int kFP = 80;   // padded feature dim (5 tiles of 16)

typedef __attribute__((ext_vector_type(4))) float f32x4;
typedef __attribute__((ext_vector_type(8))) short sv8;
typedef __attribute__((ext_vector_type(4))) unsigned u32x4;
typedef unsigned int u32;
typedef unsigned short u16;

__device__ __forceinline__ u32 pack_bf2(float a, float b) {
  __hip_bfloat16 ha = __float2bfloat16(a);
  __hip_bfloat16 hb = __float2bfloat16(b);
  u16 ua = *reinterpret_cast<u16*>(&ha);
  u16 ub = *reinterpret_cast<u16*>(&hb);
  return (u32)ua | ((u32)ub << 16);
}

__device__ __forceinline__ u16 bf16bits(float a) {
  __hip_bfloat16 h = __float2bfloat16(a);
  return *reinterpret_cast<u16*>(&h);
}

__device__ __forceinline__ float bflo(u32 v) {
  u32 x = v << 16;
  return *reinterpret_cast<float*>(&x);
}
__device__ __forceinline__ float bfhi(u32 v) {
  u32 x = v & 0xffff0000u;
  return *reinterpret_cast<float*>(&x);
}

// ---------------------------------------------------------------------------
// K1: build x0^T bf16 (B, 80, 1024).
// ---------------------------------------------------------------------------
__global__ __launch_bounds__(256) void build_x0t(
    const float* __restrict__ inputs, const float* __restrict__ h_prev,
    __hip_bfloat16* __restrict__ x0t, __hip_bfloat16* __restrict__ x0tc) {
  const int bx = blockIdx.x;
  const int b  = bx >> 4;
  const int n0 = (bx & 15) * 64;
  const int t  = threadIdx.x;

  __shared__ float hp[64][65];

  const float* hpg = h_prev + (size_t)b * kN * kU + (size_t)n0 * kU;
#pragma unroll
  for (int r = 0; r < 16; ++r) {
    int idx = t + (r << 8);
    hp[idx >> 6][idx & 63] = hpg[idx];
  }
  __syncthreads();

  {
    int u = t >> 2, g = t & 3;
    __hip_bfloat16* dst = x0t + ((size_t)b * kFP + 2 + u) * kN + n0 + g * 16;
#pragma unroll
    for (int k = 0; k < 16; ++k) dst[k] = __float2bfloat16(hp[g * 16 + k][u]);
  }

  if (t < 128) {
    int d = t & 1, nn = t >> 1;
    float v = inputs[((size_t)b * kN + n0 + nn) * 2 + d];
    __hip_bfloat16 bv = __float2bfloat16(v);
    x0t [((size_t)b * kFP + d) * kN + n0 + nn] = bv;
    x0tc[((size_t)b * kFP + d) * kN + n0 + nn] = bv;
  } else {
    int i2 = t - 128;
    __hip_bfloat16 z = __float2bfloat16(0.0f);
#pragma unroll
    for (int r = 0; r < 7; ++r) {
      int idx = i2 + r * 128;
      int row = 66 + (idx >> 6), nn = idx & 63;
      x0t [((size_t)b * kFP + row) * kN + n0 + nn] = z;
      x0tc[((size_t)b * kFP + row) * kN + n0 + nn] = z;
    }
  }
}

// ---------------------------------------------------------------------------
// K2/K4: graph-diffusion einsum, bf16 MFMA, wave-autonomous (no LDS/barriers
// in K-loop). Each wave: 16 i-rows x 2 supports x 80 f.
// A-frags: direct 64B/lane contiguous f32 reads (both s interleaved),
// packed to bf16 in-register. X-frags: direct 16B strided reads (L2-hot).
// Double-buffered register sets, unroll-by-2; compiler schedules waits.
// ---------------------------------------------------------------------------
__global__ __launch_bounds__(256, 2) void einsum_diff(
    const float* __restrict__ sup, const __hip_bfloat16* __restrict__ x0t,
    u16* __restrict__ xfeat) {
  const int bx = blockIdx.x;
  const int wk = (bx & 7) * 64 + (bx >> 3);  // XCD-chunked (512 = 8*64)
  const int t    = threadIdx.x;
  const int lane = t & 63;
  const int w    = t >> 6;                   // wave in block, 0..3
  const int q    = lane >> 4;
  const int lm   = lane & 15;

  const int gw  = wk * 4 + w;        // global wave id, 0..2047
  const int b   = gw >> 6;           // 64 waves per batch
  const int i0w = (gw & 63) * 16;    // this wave's 16-row base
  const int i0b = ((wk * 4) & 63) * 16;  // block's 64-row base

  __shared__ u16 ep[64][136];        // epilogue transpose only

  f32x4 acc[2][5];
#pragma unroll
  for (int s_ = 0; s_ < 2; ++s_)
#pragma unroll
    for (int n = 0; n < 5; ++n) acc[s_][n] = (f32x4){0.f, 0.f, 0.f, 0.f};

  // per-lane A source: row (i0w+lm), float offset q*16 within 64-float tile
  const float* aB = sup + ((size_t)b * kN + i0w + lm) * (kN * 2) + q * 16;
  // per-lane X source base
  const u16* xg2 = reinterpret_cast<const u16*>(x0t) +
                   (size_t)b * kFP * kN + (size_t)lm * kN + q * 8;

  sv8   XP[10], XQ[10];
  float4 AP[8], AQ[8];

  auto issue = [&](sv8 (&X)[10], float4 (&A)[8], int T) {
#pragma unroll
    for (int ks = 0; ks < 2; ++ks) {
#pragma unroll
      for (int r = 0; r < 4; ++r)
        A[ks * 4 + r] = *reinterpret_cast<const float4*>(
            aB + T * 128 + ks * 64 + r * 4);
#pragma unroll
      for (int n = 0; n < 5; ++n)
        X[ks * 5 + n] = *reinterpret_cast<const sv8*>(
            xg2 + (size_t)n * 16 * kN + ks * 32 + T * 64);
    }
  };

  auto step = [&](const sv8 (&X)[10], const float4 (&A)[8]) {
#pragma unroll
    for (int ks = 0; ks < 2; ++ks) {
      u32 w0[4], w1[4];
#pragma unroll
      for (int r = 0; r < 4; ++r) {
        w0[r] = pack_bf2(A[ks * 4 + r].x, A[ks * 4 + r].z);
        w1[r] = pack_bf2(A[ks * 4 + r].y, A[ks * 4 + r].w);
      }
      sv8 a0 = __builtin_bit_cast(sv8, (u32x4){w0[0], w0[1], w0[2], w0[3]});
      sv8 a1 = __builtin_bit_cast(sv8, (u32x4){w1[0], w1[1], w1[2], w1[3]});
#pragma unroll
      for (int n = 0; n < 5; ++n) {
        acc[0][n] = __builtin_amdgcn_mfma_f32_16x16x32_bf16(a0, X[ks * 5 + n], acc[0][n], 0, 0, 0);
        acc[1][n] = __builtin_amdgcn_mfma_f32_16x16x32_bf16(a1, X[ks * 5 + n], acc[1][n], 0, 0, 0);
      }
    }
  };

  issue(XP, AP, 0);
#pragma unroll 1
  for (int T2 = 0; T2 < 8; ++T2) {
    const int T = T2 * 2;
    issue(XQ, AQ, T + 1);
    step(XP, AP);
    if (T + 2 < 16) issue(XP, AP, T + 2);
    step(XQ, AQ);
  }

  // ---- epilogue: acc -> LDS bf16 [64][136] -> coalesced global ----
  __syncthreads();
#pragma unroll
  for (int s_ = 0; s_ < 2; ++s_) {
#pragma unroll
    for (int n = 0; n < 5; ++n) {
      int f = n * 16 + lm;
      if (f < 66) {
#pragma unroll
        for (int r = 0; r < 4; ++r) {
          int row = w * 16 + q * 4 + r;
          ep[row][s_ * 66 + f] = bf16bits(acc[s_][n][r]);
        }
      }
    }
  }
  __syncthreads();
  const u32* ep32 = reinterpret_cast<const u32*>(&ep[0][0]);  // [64][68]
  u32* og = reinterpret_cast<u32*>(xfeat) + ((size_t)b * kN + i0b) * 66;
#pragma unroll 1
  for (int g = t; g < 4224; g += 256) {
    int row = g / 66, c = g - row * 66;
    og[g] = ep32[row * 68 + c];
  }
}

// ---------------------------------------------------------------------------
// K3: r/u gates (xfeat bf16).
// ---------------------------------------------------------------------------
__global__ __launch_bounds__(256) void gates_ru(
    const u16* __restrict__ xfeat, const float* __restrict__ rk,
    const float* __restrict__ rbias, const float* __restrict__ uk,
    const float* __restrict__ ubias, const float* __restrict__ inputs,
    const float* __restrict__ h_prev, float* __restrict__ u_buf,
    __hip_bfloat16* __restrict__ x0tc) {
  const int row0 = blockIdx.x * 32;
  const int b = row0 >> 10, n0 = row0 & 1023;
  const int t = threadIdx.x;
  __shared__ float xm[32][134];
  __shared__ float x0s[32][66];

  {
    const u32* xsrc = reinterpret_cast<const u32*>(xfeat) + (size_t)row0 * 66;
#pragma unroll 1
    for (int g = t; g < 2112; g += 256) {
      int row = g / 66, c = g - row * 66;
      u32 v = xsrc[g];
      xm[row][c * 2]     = bflo(v);
      xm[row][c * 2 + 1] = bfhi(v);
    }
  }
#pragma unroll
  for (int r2 = 0; r2 < 8; ++r2) {
    int idx = t + (r2 << 8);
    int rw = idx >> 6, u = idx & 63;
    x0s[rw][2 + u] = h_prev[(size_t)(row0 + rw) * kU + u];
  }
  if (t < 64) x0s[t >> 1][t & 1] = inputs[(size_t)row0 * 2 + t];
  __syncthreads();

  const int cu = t & 15;
  const int rw = (t >> 4) * 2;
  float ar[2][4] = {{0.f,0.f,0.f,0.f},{0.f,0.f,0.f,0.f}};
  float au[2][4] = {{0.f,0.f,0.f,0.f},{0.f,0.f,0.f,0.f}};

#pragma unroll 4
  for (int f = 0; f < 66; ++f) {  // m = 0
    float4 vr = *reinterpret_cast<const float4*>(rk + (size_t)(f * 3) * kU + cu * 4);
    float4 vu = *reinterpret_cast<const float4*>(uk + (size_t)(f * 3) * kU + cu * 4);
    float a0 = x0s[rw][f], a1 = x0s[rw + 1][f];
    ar[0][0] += a0 * vr.x; ar[0][1] += a0 * vr.y; ar[0][2] += a0 * vr.z; ar[0][3] += a0 * vr.w;
    ar[1][0] += a1 * vr.x; ar[1][1] += a1 * vr.y; ar[1][2] += a1 * vr.z; ar[1][3] += a1 * vr.w;
    au[0][0] += a0 * vu.x; au[0][1] += a0 * vu.y; au[0][2] += a0 * vu.z; au[0][3] += a0 * vu.w;
    au[1][0] += a1 * vu.x; au[1][1] += a1 * vu.y; au[1][2] += a1 * vu.z; au[1][3] += a1 * vu.w;
  }
#pragma unroll
  for (int m = 1; m <= 2; ++m) {
#pragma unroll 4
    for (int f = 0; f < 66; ++f) {
      float4 vr = *reinterpret_cast<const float4*>(rk + (size_t)(f * 3 + m) * kU + cu * 4);
      float4 vu = *reinterpret_cast<const float4*>(uk + (size_t)(f * 3 + m) * kU + cu * 4);
      float a0 = xm[rw][(m - 1) * 66 + f], a1 = xm[rw + 1][(m - 1) * 66 + f];
      ar[0][0] += a0 * vr.x; ar[0][1] += a0 * vr.y; ar[0][2] += a0 * vr.z; ar[0][3] += a0 * vr.w;
      ar[1][0] += a1 * vr.x; ar[1][1] += a1 * vr.y; ar[1][2] += a1 * vr.z; ar[1][3] += a1 * vr.w;
      au[0][0] += a0 * vu.x; au[0][1] += a0 * vu.y; au[0][2] += a0 * vu.z; au[0][3] += a0 * vu.w;
      au[1][0] += a1 * vu.x; au[1][1] += a1 * vu.y; au[1][2] += a1 * vu.z; au[1][3] += a1 * vu.w;
    }
  }

#pragma unroll
  for (int rr = 0; rr < 2; ++rr) {
    int grow = row0 + rw + rr;
    int n = n0 + rw + rr;
#pragma unroll
    for (int j = 0; j < 4; ++j) {
      int u = cu * 4 + j;
      float rv = 1.f / (1.f + __expf(-(ar[rr][j] + rbias[u])));
      float uv = 1.f / (1.f + __expf(-(au[rr][j] + ubias[u])));
      u_buf[(size_t)grow * kU + u] = uv;
      float rh = rv * h_prev[(size_t)grow * kU + u];
      x0tc[((size_t)b * kFP + 2 + u) * kN + n] = __float2bfloat16(rh);
    }
  }
}

// ---------------------------------------------------------------------------
// K5: c gate + GRU update (xfeat bf16).
// ---------------------------------------------------------------------------
__global__ __launch_bounds__(256) void gate_c_final(
    const u16* __restrict__ xfeat, const float* __restrict__ ck,
    const float* __restrict__ cbias, const float* __restrict__ inputs,
    const __hip_bfloat16* __restrict__ x0tc, const float* __restrict__ h_prev,
    const float* __restrict__ u_buf, float* __restrict__ out) {
  const int row0 = blockIdx.x * 32;
  const int b = row0 >> 10, n0 = row0 & 1023;
  const int t = threadIdx.x;
  __shared__ float xm[32][134];
  __shared__ float x0c[32][66];

  {
    const u32* xsrc = reinterpret_cast<const u32*>(xfeat) + (size_t)row0 * 66;
#pragma unroll 1
    for (int g = t; g < 2112; g += 256) {
      int row = g / 66, c = g - row * 66;
      u32 v = xsrc[g];
      xm[row][c * 2]     = bflo(v);
      xm[row][c * 2 + 1] = bfhi(v);
    }
  }
#pragma unroll
  for (int r2 = 0; r2 < 8; ++r2) {
    int idx = t + (r2 << 8);
    int u = idx >> 5, nn = idx & 31;
    x0c[nn][2 + u] =
        __bfloat162float(x0tc[((size_t)b * kFP + 2 + u) * kN + n0 + nn]);
  }
  if (t < 64) x0c[t >> 1][t & 1] = inputs[(size_t)row0 * 2 + t];
  __syncthreads();

  const int cu = t & 15;
  const int rw = (t >> 4) * 2;
  float ac[2][4] = {{0.f,0.f,0.f,0.f},{0.f,0.f,0.f,0.f}};

#pragma unroll 4
  for (int f = 0; f < 66; ++f) {  // m = 0
    float4 vc = *reinterpret_cast<const float4*>(ck + (size_t)(f * 3) * kU + cu * 4);
    float a0 = x0c[rw][f], a1 = x0c[rw + 1][f];
    ac[0][0] += a0 * vc.x; ac[0][1] += a0 * vc.y; ac[0][2] += a0 * vc.z; ac[0][3] += a0 * vc.w;
    ac[1][0] += a1 * vc.x; ac[1][1] += a1 * vc.y; ac[1][2] += a1 * vc.z; ac[1][3] += a1 * vc.w;
  }
#pragma unroll
  for (int m = 1; m <= 2; ++m) {
#pragma unroll 4
    for (int f = 0; f < 66; ++f) {
      float4 vc = *reinterpret_cast<const float4*>(ck + (size_t)(f * 3 + m) * kU + cu * 4);
      float a0 = xm[rw][(m - 1) * 66 + f], a1 = xm[rw + 1][(m - 1) * 66 + f];
      ac[0][0] += a0 * vc.x; ac[0][1] += a0 * vc.y; ac[0][2] += a0 * vc.z; ac[0][3] += a0 * vc.w;
      ac[1][0] += a1 * vc.x; ac[1][1] += a1 * vc.y; ac[1][2] += a1 * vc.z; ac[1][3] += a1 * vc.w;
    }
  }

#pragma unroll
  for (int rr = 0; rr < 2; ++rr) {
    int grow = row0 + rw + rr;
#pragma unroll
    for (int j = 0; j < 4; ++j) {
      int u = cu * 4 + j;
      float cv = tanhf(ac[rr][j] + cbias[u]);
      float uv = u_buf[(size_t)grow * kU + u];
      float hp = h_prev[(size_t)grow * kU + u];
      out[(size_t)grow * kU + u] = uv * hp + (1.f - uv) * cv;
    }
  }
}

}  // namespace

extern "C" void kernel_launch(void* const* d_in, const int* in_sizes, int n_in,
                              void* d_out, int out_size, void* d_ws, size_t ws_size,
                              hipStream_t stream) {
  const float* inputs = (const float*)d_in[0];
  const float* sup    = (const float*)d_in[1];
  const float* h_prev = (const float*)d_in[2];
  const float* rk     = (const float*)d_in[3];
  const float* rbias  = (const float*)d_in[4];
  const float* uk     = (const float*)d_in[5];
  const float* ubias  = (const float*)d_in[6];
  const float* ck     = (const float*)d_in[7];
  const float* cbias  = (const float*)d_in[8];
  float* out = (float*)d_out;

  char* ws = (char*)d_ws;
  __hip_bfloat16* x0t   = (__hip_bfloat16*)(ws);                    //  5,242,880 B
  __hip_bfloat16* x0tc  = (__hip_bfloat16*)(ws + 5242880);          //  5,242,880 B
  u16*            xfeat = (u16*)(ws + 10485760);                    //  8,650,752 B
  float*          u_buf = (float*)(ws + 19136512);                  //  8,388,608 B

  hipLaunchKernelGGL(build_x0t, dim3(512), dim3(256), 0, stream,
                     inputs, h_prev, x0t, x0tc);
  hipLaunchKernelGGL(einsum_diff, dim3(512), dim3(256), 0, stream,
                     sup, x0t, xfeat);
  hipLaunchKernelGGL(gates_ru, dim3(1024), dim3(256), 0, stream,
                     xfeat, rk, rbias, uk, ubias, inputs, h_prev, u_buf, x0tc);
  hipLaunchKernelGGL(einsum_diff, dim3(512), dim3(256), 0, stream,
                     sup, x0tc, xfeat);
  hipLaunchKernelGGL(gate_c_final, dim3(1024), dim3(256), 0, stream,
                     xfeat, ck, cbias, inputs, x0tc, h_prev, u_buf, out);
}

// Round 6
// 247.011 us; speedup vs baseline: 1.0784x; 1.0784x over previous
//
#include <hip/hip_runtime.h>
#include <hip/hip_bf16.h>

namespace {

constexpr int kN  = 1024;
constexpr int kU  = 64;
constexpr int kFP = 80;   // padded feature dim (5 tiles of 16)

typedef __attribute__((ext_vector_type(4))) float f32x4;
typedef __attribute__((ext_vector_type(8))) short sv8;
typedef unsigned int u32;
typedef unsigned short u16;

__device__ __forceinline__ u32 pack_bf2(float a, float b) {
  __hip_bfloat16 ha = __float2bfloat16(a);
  __hip_bfloat16 hb = __float2bfloat16(b);
  u16 ua = *reinterpret_cast<u16*>(&ha);
  u16 ub = *reinterpret_cast<u16*>(&hb);
  return (u32)ua | ((u32)ub << 16);
}

__device__ __forceinline__ u16 bf16bits(float a) {
  __hip_bfloat16 h = __float2bfloat16(a);
  return *reinterpret_cast<u16*>(&h);
}

__device__ __forceinline__ float bflo(u32 v) {
  u32 x = v << 16;
  return *reinterpret_cast<float*>(&x);
}
__device__ __forceinline__ float bfhi(u32 v) {
  u32 x = v & 0xffff0000u;
  return *reinterpret_cast<float*>(&x);
}

__device__ __forceinline__ void gl16(const void* g, void* l) {
  __builtin_amdgcn_global_load_lds(
      (const __attribute__((address_space(1))) u32*)g,
      (__attribute__((address_space(3))) u32*)l, 16, 0, 0);
}

// ---------------------------------------------------------------------------
// K1: build x0^T bf16 (B, 80, 1024).
// ---------------------------------------------------------------------------
__global__ __launch_bounds__(256) void build_x0t(
    const float* __restrict__ inputs, const float* __restrict__ h_prev,
    __hip_bfloat16* __restrict__ x0t, __hip_bfloat16* __restrict__ x0tc) {
  const int bx = blockIdx.x;
  const int b  = bx >> 4;
  const int n0 = (bx & 15) * 64;
  const int t  = threadIdx.x;

  __shared__ float hp[64][65];

  const float* hpg = h_prev + (size_t)b * kN * kU + (size_t)n0 * kU;
#pragma unroll
  for (int r = 0; r < 16; ++r) {
    int idx = t + (r << 8);
    hp[idx >> 6][idx & 63] = hpg[idx];
  }
  __syncthreads();

  {
    int u = t >> 2, g = t & 3;
    __hip_bfloat16* dst = x0t + ((size_t)b * kFP + 2 + u) * kN + n0 + g * 16;
#pragma unroll
    for (int k = 0; k < 16; ++k) dst[k] = __float2bfloat16(hp[g * 16 + k][u]);
  }

  if (t < 128) {
    int d = t & 1, nn = t >> 1;
    float v = inputs[((size_t)b * kN + n0 + nn) * 2 + d];
    __hip_bfloat16 bv = __float2bfloat16(v);
    x0t [((size_t)b * kFP + d) * kN + n0 + nn] = bv;
    x0tc[((size_t)b * kFP + d) * kN + n0 + nn] = bv;
  } else {
    int i2 = t - 128;
    __hip_bfloat16 z = __float2bfloat16(0.0f);
#pragma unroll
    for (int r = 0; r < 7; ++r) {
      int idx = i2 + r * 128;
      int row = 66 + (idx >> 6), nn = idx & 63;
      x0t [((size_t)b * kFP + row) * kN + n0 + nn] = z;
      x0tc[((size_t)b * kFP + row) * kN + n0 + nn] = z;
    }
  }
}

// ---------------------------------------------------------------------------
// K2/K4: graph-diffusion einsum, bf16 MFMA, BK=128 (1KB per row per visit
// for DRAM row-buffer locality). 512 thr / 8 waves = s(2) x ih(4) / 64 rows
// per block / grid 512 (2 blocks/CU). Single-buffered LDS (A 32KB + X 20KB),
// T14 split staging: A(t+1)->regs issued before compute(t); X via
// global_load_lds after the read-barrier; counted vmcnt; raw barriers.
// ---------------------------------------------------------------------------
__global__ __launch_bounds__(512, 4) void einsum_diff(
    const float* __restrict__ sup, const __hip_bfloat16* __restrict__ x0t,
    u16* __restrict__ xfeat) {
  const int bx = blockIdx.x;
  const int wk = (bx & 7) * 64 + (bx >> 3);  // XCD-chunked (512 = 8*64)
  const int b  = wk >> 4;
  const int i0 = (wk & 15) << 6;
  const int t    = threadIdx.x;
  const int lane = t & 63;
  const int w    = t >> 6;       // 0..7
  const int q    = lane >> 4;
  const int lm   = lane & 15;
  const int s    = w & 1;
  const int ih   = w >> 1;       // 0..3

  __shared__ u16 Af[2][4][4][64][8];  // [s][ks][ihh][slot(ks-xor)][8] 32KB
  __shared__ u16 Xf[20][64][8];       // [ks*5+n][lane][8]            20KB

  f32x4 acc[5];
#pragma unroll
  for (int n = 0; n < 5; ++n) acc[n] = (f32x4){0.f, 0.f, 0.f, 0.f};

  // ---- A staging: thread (row ii, part p); 128B contiguous per visit ----
  const int ii = t >> 3, p = t & 7;
  const float* aSrc = sup + ((size_t)b * kN + i0 + ii) * (kN * 2) + p * 32;
  const int ksA  = p >> 1;
  const int q0   = (p & 1) * 2;
  const int ihhA = ii >> 4;
  const int lmA  = (ii & 15) ^ (ksA << 1);  // ks-XOR de-conflicts writes

  // ---- X DMA sources: wave w -> segs w, w+8, (w<4) w+16 ----
  const u16* xg = reinterpret_cast<const u16*>(x0t) + (size_t)b * kFP * kN;
  const int segA_ = w, segB_ = w + 8, segC_ = w + 16;
  const u16* xs1 = xg + (size_t)((segA_ % 5) * 16 + lm) * kN + (segA_ / 5) * 32 + q * 8;
  const u16* xs2 = xg + (size_t)((segB_ % 5) * 16 + lm) * kN + (segB_ / 5) * 32 + q * 8;
  const u16* xs3 = (w < 4)
      ? xg + (size_t)((segC_ % 5) * 16 + lm) * kN + (segC_ / 5) * 32 + q * 8
      : nullptr;

  auto dmaX = [&](int T) {
    int jo = T * 128;
    gl16(xs1 + jo, &Xf[segA_][0][0]);
    gl16(xs2 + jo, &Xf[segB_][0][0]);
    if (w < 4) gl16(xs3 + jo, &Xf[segC_][0][0]);
  };

  float4 R[8];
  auto loadA = [&](int T) {
    const float* pp = aSrc + (size_t)T * 256;
#pragma unroll
    for (int r = 0; r < 8; ++r)
      R[r] = *reinterpret_cast<const float4*>(pp + r * 4);
  };

  auto writeA = [&]() {
    u32 w0[8], w1[8];
#pragma unroll
    for (int k = 0; k < 8; ++k) {
      w0[k] = pack_bf2(R[k].x, R[k].z);
      w1[k] = pack_bf2(R[k].y, R[k].w);
    }
    uint4* d;
    d = reinterpret_cast<uint4*>(&Af[0][ksA][ihhA][q0 * 16 + lmA][0]);
    *d = (uint4){w0[0], w0[1], w0[2], w0[3]};
    d = reinterpret_cast<uint4*>(&Af[0][ksA][ihhA][(q0 + 1) * 16 + lmA][0]);
    *d = (uint4){w0[4], w0[5], w0[6], w0[7]};
    d = reinterpret_cast<uint4*>(&Af[1][ksA][ihhA][q0 * 16 + lmA][0]);
    *d = (uint4){w1[0], w1[1], w1[2], w1[3]};
    d = reinterpret_cast<uint4*>(&Af[1][ksA][ihhA][(q0 + 1) * 16 + lmA][0]);
    *d = (uint4){w1[4], w1[5], w1[6], w1[7]};
  };

  auto compute = [&]() {
#pragma unroll
    for (int ks = 0; ks < 4; ++ks) {
      sv8 a = *reinterpret_cast<const sv8*>(
          &Af[s][ks][ih][q * 16 + (lm ^ (ks << 1))][0]);
#pragma unroll
      for (int n = 0; n < 5; ++n) {
        sv8 xb = *reinterpret_cast<const sv8*>(&Xf[ks * 5 + n][lane][0]);
        acc[n] = __builtin_amdgcn_mfma_f32_16x16x32_bf16(a, xb, acc[n], 0, 0, 0);
      }
    }
  };

  // ---- prologue: stage tile 0 ----
  loadA(0);
  dmaX(0);
  asm volatile("s_waitcnt vmcnt(0)" ::: "memory");
  writeA();
  asm volatile("s_waitcnt lgkmcnt(0)" ::: "memory");
  __builtin_amdgcn_s_barrier();
  __builtin_amdgcn_sched_barrier(0);

#pragma unroll 1
  for (int T = 0; T < 8; ++T) {
    if (T < 7) loadA(T + 1);   // A(t+1) in flight across compute
    compute();
    __builtin_amdgcn_s_barrier();          // all reads of buffers done
    __builtin_amdgcn_sched_barrier(0);
    if (T < 7) {
      dmaX(T + 1);                          // X(t+1) DMA into freed buffer
      if (w < 4) { asm volatile("s_waitcnt vmcnt(3)" ::: "memory"); }
      else       { asm volatile("s_waitcnt vmcnt(2)" ::: "memory"); }
      writeA();                             // A regs arrived; pack+write
      asm volatile("s_waitcnt vmcnt(0) lgkmcnt(0)" ::: "memory");
      __builtin_amdgcn_s_barrier();
      __builtin_amdgcn_sched_barrier(0);
    }
  }

  // ---- epilogue: acc -> LDS bf16 [64][136] -> coalesced global ----
  __builtin_amdgcn_s_barrier();
  u16* ep = (u16*)&Af[0][0][0][0][0];
#pragma unroll
  for (int n = 0; n < 5; ++n) {
    int f = n * 16 + lm;
    if (f < 66) {
#pragma unroll
      for (int r = 0; r < 4; ++r) {
        int row = ih * 16 + q * 4 + r;
        ep[row * 136 + s * 66 + f] = bf16bits(acc[n][r]);
      }
    }
  }
  __syncthreads();
  const u32* ep32 = reinterpret_cast<const u32*>(ep);  // [64][68]
  u32* og = reinterpret_cast<u32*>(xfeat) + ((size_t)b * kN + i0) * 66;
#pragma unroll 1
  for (int g = t; g < 4224; g += 512) {
    int row = g / 66, c = g - row * 66;
    og[g] = ep32[row * 68 + c];
  }
}

// ---------------------------------------------------------------------------
// K3: r/u gates (xfeat bf16).
// ---------------------------------------------------------------------------
__global__ __launch_bounds__(256) void gates_ru(
    const u16* __restrict__ xfeat, const float* __restrict__ rk,
    const float* __restrict__ rbias, const float* __restrict__ uk,
    const float* __restrict__ ubias, const float* __restrict__ inputs,
    const float* __restrict__ h_prev, float* __restrict__ u_buf,
    __hip_bfloat16* __restrict__ x0tc) {
  const int row0 = blockIdx.x * 32;
  const int b = row0 >> 10, n0 = row0 & 1023;
  const int t = threadIdx.x;
  __shared__ float xm[32][134];
  __shared__ float x0s[32][66];

  {
    const u32* xsrc = reinterpret_cast<const u32*>(xfeat) + (size_t)row0 * 66;
#pragma unroll 1
    for (int g = t; g < 2112; g += 256) {
      int row = g / 66, c = g - row * 66;
      u32 v = xsrc[g];
      xm[row][c * 2]     = bflo(v);
      xm[row][c * 2 + 1] = bfhi(v);
    }
  }
#pragma unroll
  for (int r2 = 0; r2 < 8; ++r2) {
    int idx = t + (r2 << 8);
    int rw = idx >> 6, u = idx & 63;
    x0s[rw][2 + u] = h_prev[(size_t)(row0 + rw) * kU + u];
  }
  if (t < 64) x0s[t >> 1][t & 1] = inputs[(size_t)row0 * 2 + t];
  __syncthreads();

  const int cu = t & 15;
  const int rw = (t >> 4) * 2;
  float ar[2][4] = {{0.f,0.f,0.f,0.f},{0.f,0.f,0.f,0.f}};
  float au[2][4] = {{0.f,0.f,0.f,0.f},{0.f,0.f,0.f,0.f}};

#pragma unroll 4
  for (int f = 0; f < 66; ++f) {  // m = 0
    float4 vr = *reinterpret_cast<const float4*>(rk + (size_t)(f * 3) * kU + cu * 4);
    float4 vu = *reinterpret_cast<const float4*>(uk + (size_t)(f * 3) * kU + cu * 4);
    float a0 = x0s[rw][f], a1 = x0s[rw + 1][f];
    ar[0][0] += a0 * vr.x; ar[0][1] += a0 * vr.y; ar[0][2] += a0 * vr.z; ar[0][3] += a0 * vr.w;
    ar[1][0] += a1 * vr.x; ar[1][1] += a1 * vr.y; ar[1][2] += a1 * vr.z; ar[1][3] += a1 * vr.w;
    au[0][0] += a0 * vu.x; au[0][1] += a0 * vu.y; au[0][2] += a0 * vu.z; au[0][3] += a0 * vu.w;
    au[1][0] += a1 * vu.x; au[1][1] += a1 * vu.y; au[1][2] += a1 * vu.z; au[1][3] += a1 * vu.w;
  }
#pragma unroll
  for (int m = 1; m <= 2; ++m) {
#pragma unroll 4
    for (int f = 0; f < 66; ++f) {
      float4 vr = *reinterpret_cast<const float4*>(rk + (size_t)(f * 3 + m) * kU + cu * 4);
      float4 vu = *reinterpret_cast<const float4*>(uk + (size_t)(f * 3 + m) * kU + cu * 4);
      float a0 = xm[rw][(m - 1) * 66 + f], a1 = xm[rw + 1][(m - 1) * 66 + f];
      ar[0][0] += a0 * vr.x; ar[0][1] += a0 * vr.y; ar[0][2] += a0 * vr.z; ar[0][3] += a0 * vr.w;
      ar[1][0] += a1 * vr.x; ar[1][1] += a1 * vr.y; ar[1][2] += a1 * vr.z; ar[1][3] += a1 * vr.w;
      au[0][0] += a0 * vu.x; au[0][1] += a0 * vu.y; au[0][2] += a0 * vu.z; au[0][3] += a0 * vu.w;
      au[1][0] += a1 * vu.x; au[1][1] += a1 * vu.y; au[1][2] += a1 * vu.z; au[1][3] += a1 * vu.w;
    }
  }

#pragma unroll
  for (int rr = 0; rr < 2; ++rr) {
    int grow = row0 + rw + rr;
    int n = n0 + rw + rr;
#pragma unroll
    for (int j = 0; j < 4; ++j) {
      int u = cu * 4 + j;
      float rv = 1.f / (1.f + __expf(-(ar[rr][j] + rbias[u])));
      float uv = 1.f / (1.f + __expf(-(au[rr][j] + ubias[u])));
      u_buf[(size_t)grow * kU + u] = uv;
      float rh = rv * h_prev[(size_t)grow * kU + u];
      x0tc[((size_t)b * kFP + 2 + u) * kN + n] = __float2bfloat16(rh);
    }
  }
}

// ---------------------------------------------------------------------------
// K5: c gate + GRU update (xfeat bf16).
// ---------------------------------------------------------------------------
__global__ __launch_bounds__(256) void gate_c_final(
    const u16* __restrict__ xfeat, const float* __restrict__ ck,
    const float* __restrict__ cbias, const float* __restrict__ inputs,
    const __hip_bfloat16* __restrict__ x0tc, const float* __restrict__ h_prev,
    const float* __restrict__ u_buf, float* __restrict__ out) {
  const int row0 = blockIdx.x * 32;
  const int b = row0 >> 10, n0 = row0 & 1023;
  const int t = threadIdx.x;
  __shared__ float xm[32][134];
  __shared__ float x0c[32][66];

  {
    const u32* xsrc = reinterpret_cast<const u32*>(xfeat) + (size_t)row0 * 66;
#pragma unroll 1
    for (int g = t; g < 2112; g += 256) {
      int row = g / 66, c = g - row * 66;
      u32 v = xsrc[g];
      xm[row][c * 2]     = bflo(v);
      xm[row][c * 2 + 1] = bfhi(v);
    }
  }
#pragma unroll
  for (int r2 = 0; r2 < 8; ++r2) {
    int idx = t + (r2 << 8);
    int u = idx >> 5, nn = idx & 31;
    x0c[nn][2 + u] =
        __bfloat162float(x0tc[((size_t)b * kFP + 2 + u) * kN + n0 + nn]);
  }
  if (t < 64) x0c[t >> 1][t & 1] = inputs[(size_t)row0 * 2 + t];
  __syncthreads();

  const int cu = t & 15;
  const int rw = (t >> 4) * 2;
  float ac[2][4] = {{0.f,0.f,0.f,0.f},{0.f,0.f,0.f,0.f}};

#pragma unroll 4
  for (int f = 0; f < 66; ++f) {  // m = 0
    float4 vc = *reinterpret_cast<const float4*>(ck + (size_t)(f * 3) * kU + cu * 4);
    float a0 = x0c[rw][f], a1 = x0c[rw + 1][f];
    ac[0][0] += a0 * vc.x; ac[0][1] += a0 * vc.y; ac[0][2] += a0 * vc.z; ac[0][3] += a0 * vc.w;
    ac[1][0] += a1 * vc.x; ac[1][1] += a1 * vc.y; ac[1][2] += a1 * vc.z; ac[1][3] += a1 * vc.w;
  }
#pragma unroll
  for (int m = 1; m <= 2; ++m) {
#pragma unroll 4
    for (int f = 0; f < 66; ++f) {
      float4 vc = *reinterpret_cast<const float4*>(ck + (size_t)(f * 3 + m) * kU + cu * 4);
      float a0 = xm[rw][(m - 1) * 66 + f], a1 = xm[rw + 1][(m - 1) * 66 + f];
      ac[0][0] += a0 * vc.x; ac[0][1] += a0 * vc.y; ac[0][2] += a0 * vc.z; ac[0][3] += a0 * vc.w;
      ac[1][0] += a1 * vc.x; ac[1][1] += a1 * vc.y; ac[1][2] += a1 * vc.z; ac[1][3] += a1 * vc.w;
    }
  }

#pragma unroll
  for (int rr = 0; rr < 2; ++rr) {
    int grow = row0 + rw + rr;
#pragma unroll
    for (int j = 0; j < 4; ++j) {
      int u = cu * 4 + j;
      float cv = tanhf(ac[rr][j] + cbias[u]);
      float uv = u_buf[(size_t)grow * kU + u];
      float hp = h_prev[(size_t)grow * kU + u];
      out[(size_t)grow * kU + u] = uv * hp + (1.f - uv) * cv;
    }
  }
}

}  // namespace

extern "C" void kernel_launch(void* const* d_in, const int* in_sizes, int n_in,
                              void* d_out, int out_size, void* d_ws, size_t ws_size,
                              hipStream_t stream) {
  const float* inputs = (const float*)d_in[0];
  const float* sup    = (const float*)d_in[1];
  const float* h_prev = (const float*)d_in[2];
  const float* rk     = (const float*)d_in[3];
  const float* rbias  = (const float*)d_in[4];
  const float* uk     = (const float*)d_in[5];
  const float* ubias  = (const float*)d_in[6];
  const float* ck     = (const float*)d_in[7];
  const float* cbias  = (const float*)d_in[8];
  float* out = (float*)d_out;

  char* ws = (char*)d_ws;
  __hip_bfloat16* x0t   = (__hip_bfloat16*)(ws);                    //  5,242,880 B
  __hip_bfloat16* x0tc  = (__hip_bfloat16*)(ws + 5242880);          //  5,242,880 B
  u16*            xfeat = (u16*)(ws + 10485760);                    //  8,650,752 B
  float*          u_buf = (float*)(ws + 19136512);                  //  8,388,608 B

  hipLaunchKernelGGL(build_x0t, dim3(512), dim3(256), 0, stream,
                     inputs, h_prev, x0t, x0tc);
  hipLaunchKernelGGL(einsum_diff, dim3(512), dim3(512), 0, stream,
                     sup, x0t, xfeat);
  hipLaunchKernelGGL(gates_ru, dim3(1024), dim3(256), 0, stream,
                     xfeat, rk, rbias, uk, ubias, inputs, h_prev, u_buf, x0tc);
  hipLaunchKernelGGL(einsum_diff, dim3(512), dim3(512), 0, stream,
                     sup, x0tc, xfeat);
  hipLaunchKernelGGL(gate_c_final, dim3(1024), dim3(256), 0, stream,
                     xfeat, ck, cbias, inputs, x0tc, h_prev, u_buf, out);
}

// Round 7
// 223.279 us; speedup vs baseline: 1.1930x; 1.1063x over previous
//
#include <hip/hip_runtime.h>
#include <hip/hip_bf16.h>

namespace {

constexpr int kN  = 1024;
constexpr int kU  = 64;
constexpr int kFP = 80;   // padded feature dim (5 tiles of 16)

typedef __attribute__((ext_vector_type(4))) float f32x4;
typedef __attribute__((ext_vector_type(8))) short sv8;
typedef unsigned int u32;
typedef unsigned short u16;

__device__ __forceinline__ u32 pack_bf2(float a, float b) {
  __hip_bfloat16 ha = __float2bfloat16(a);
  __hip_bfloat16 hb = __float2bfloat16(b);
  u16 ua = *reinterpret_cast<u16*>(&ha);
  u16 ub = *reinterpret_cast<u16*>(&hb);
  return (u32)ua | ((u32)ub << 16);
}

__device__ __forceinline__ u16 bf16bits(float a) {
  __hip_bfloat16 h = __float2bfloat16(a);
  return *reinterpret_cast<u16*>(&h);
}

__device__ __forceinline__ float bflo(u32 v) {
  u32 x = v << 16;
  return *reinterpret_cast<float*>(&x);
}
__device__ __forceinline__ float bfhi(u32 v) {
  u32 x = v & 0xffff0000u;
  return *reinterpret_cast<float*>(&x);
}

__device__ __forceinline__ void gl16(const void* g, void* l) {
  __builtin_amdgcn_global_load_lds(
      (const __attribute__((address_space(1))) u32*)g,
      (__attribute__((address_space(3))) u32*)l, 16, 0, 0);
}

// ---------------------------------------------------------------------------
// K0: supports f32 -> bf16 (s-interleaved), pure linear stream.
// Nontemporal f32 reads keep the dead source stream out of L3 so the 128 MB
// bf16 output stays Infinity-Cache-resident for both einsum passes.
// ---------------------------------------------------------------------------
__global__ __launch_bounds__(256) void convert_sup(
    const f32x4* __restrict__ sup4, uint2* __restrict__ outb) {
  const size_t n4 = (size_t)16 * 1024 * 1024;  // 64M floats / 4
  size_t idx = (size_t)blockIdx.x * 256 + threadIdx.x;
  const size_t stride = (size_t)gridDim.x * 256;
#pragma unroll 1
  for (; idx < n4; idx += stride) {
    f32x4 v = __builtin_nontemporal_load(sup4 + idx);
    uint2 o;
    o.x = pack_bf2(v[0], v[1]);   // j even: (s0,s1)
    o.y = pack_bf2(v[2], v[3]);   // j odd : (s0,s1)
    outb[idx] = o;
  }
}

// ---------------------------------------------------------------------------
// K1: build x0^T bf16 (B, 80, 1024).
// ---------------------------------------------------------------------------
__global__ __launch_bounds__(256) void build_x0t(
    const float* __restrict__ inputs, const float* __restrict__ h_prev,
    __hip_bfloat16* __restrict__ x0t, __hip_bfloat16* __restrict__ x0tc) {
  const int bx = blockIdx.x;
  const int b  = bx >> 4;
  const int n0 = (bx & 15) * 64;
  const int t  = threadIdx.x;

  __shared__ float hp[64][65];

  const float* hpg = h_prev + (size_t)b * kN * kU + (size_t)n0 * kU;
#pragma unroll
  for (int r = 0; r < 16; ++r) {
    int idx = t + (r << 8);
    hp[idx >> 6][idx & 63] = hpg[idx];
  }
  __syncthreads();

  {
    int u = t >> 2, g = t & 3;
    __hip_bfloat16* dst = x0t + ((size_t)b * kFP + 2 + u) * kN + n0 + g * 16;
#pragma unroll
    for (int k = 0; k < 16; ++k) dst[k] = __float2bfloat16(hp[g * 16 + k][u]);
  }

  if (t < 128) {
    int d = t & 1, nn = t >> 1;
    float v = inputs[((size_t)b * kN + n0 + nn) * 2 + d];
    __hip_bfloat16 bv = __float2bfloat16(v);
    x0t [((size_t)b * kFP + d) * kN + n0 + nn] = bv;
    x0tc[((size_t)b * kFP + d) * kN + n0 + nn] = bv;
  } else {
    int i2 = t - 128;
    __hip_bfloat16 z = __float2bfloat16(0.0f);
#pragma unroll
    for (int r = 0; r < 7; ++r) {
      int idx = i2 + r * 128;
      int row = 66 + (idx >> 6), nn = idx & 63;
      x0t [((size_t)b * kFP + row) * kN + n0 + nn] = z;
      x0tc[((size_t)b * kFP + row) * kN + n0 + nn] = z;
    }
  }
}

// ---------------------------------------------------------------------------
// K2/K4: graph-diffusion einsum, bf16 MFMA. A read from bf16 supb
// (L3-resident, half the bytes, no cvt in loop). R4 structure: 512 thr,
// 8 waves = s(2) x ih(4), 64-row i-tile, grid 512 (2/CU), double-buffered
// LDS, 2-phase pipeline with raw barriers. Af properly sized (32 KB).
// ---------------------------------------------------------------------------
__global__ __launch_bounds__(512, 4) void einsum_diff(
    const u32* __restrict__ supb, const __hip_bfloat16* __restrict__ x0t,
    u16* __restrict__ xfeat) {
  const int bx = blockIdx.x;
  const int wk = (bx & 7) * 64 + (bx >> 3);  // XCD-chunked (512 = 8*64)
  const int b  = wk >> 4;
  const int i0 = (wk & 15) << 6;
  const int t    = threadIdx.x;
  const int lane = t & 63;
  const int w    = t >> 6;       // 0..7
  const int q    = lane >> 4;
  const int lm   = lane & 15;
  const int s    = w & 1;
  const int ih   = w >> 1;       // 0..3

  __shared__ u16 Af[2][2][2][4][64][8];  // [buf][s][ks][ihh][slot][8]  32 KB
  __shared__ u16 Xf[2][10][64][8];       // [buf][ks*5+n][lane][8]      20 KB

  f32x4 acc[5];
#pragma unroll
  for (int n = 0; n < 5; ++n) acc[n] = (f32x4){0.f, 0.f, 0.f, 0.f};

  const u32* sb = supb + ((size_t)b * kN + i0) * kN;
  const u16* xg = reinterpret_cast<const u16*>(x0t) + (size_t)b * kFP * kN;

  // ---- A staging unit: thread -> (row ii, j8-group jb), 32 B contiguous ----
  const int ii = t >> 3, jb = t & 7;
  const u32* aSrc = sb + (size_t)ii * kN + jb * 8;
  const int ksA = jb >> 2, q2 = jb & 3;
  const int ihhA = ii >> 4, lm2 = ii & 15;
  const int aOff = ksA * 4096 + ihhA * 1024 +
                   (((q2 * 16 + lm2) * 16) ^ (q2 << 4) ^ (ksA << 6));
  char* const afBase = (char*)&Af[0][0][0][0][0][0];

  // ---- X DMA sources (seg = ks*5+n); wave w -> seg w, (w<2) seg w+8 ----
  const int seg1 = w;
  const int seg2 = w + 8;
  const u16* xs1 =
      xg + (size_t)((seg1 % 5) * 16 + lm) * kN + (seg1 / 5) * 32 + q * 8;
  const u16* xs2 = (w < 2)
      ? xg + (size_t)((seg2 % 5) * 16 + lm) * kN + (seg2 / 5) * 32 + q * 8
      : nullptr;

  uint4 W1, W2;

  auto dmaX = [&](int nb, int T) {
    int jo = T * 64;
    gl16(xs1 + jo, &Xf[nb][seg1][0][0]);
    if (w < 2) gl16(xs2 + jo, &Xf[nb][seg2][0][0]);
  };

  auto loadA = [&](int T) {
    const u32* p = aSrc + T * 64;
    W1 = *reinterpret_cast<const uint4*>(p);
    W2 = *reinterpret_cast<const uint4*>(p + 4);
  };

  auto packWrite = [&](int nb) {
    // de-interleave (j,s): u32 = [lo: s0, hi: s1] per j
    u32 p0[4], p1[4];
    p0[0] = (W1.x & 0xffffu) | (W1.y << 16);
    p0[1] = (W1.z & 0xffffu) | (W1.w << 16);
    p0[2] = (W2.x & 0xffffu) | (W2.y << 16);
    p0[3] = (W2.z & 0xffffu) | (W2.w << 16);
    p1[0] = (W1.x >> 16) | (W1.y & 0xffff0000u);
    p1[1] = (W1.z >> 16) | (W1.w & 0xffff0000u);
    p1[2] = (W2.x >> 16) | (W2.y & 0xffff0000u);
    p1[3] = (W2.z >> 16) | (W2.w & 0xffff0000u);
    char* base = afBase + nb * 16384 + aOff;
    *reinterpret_cast<uint4*>(base)        = (uint4){p0[0], p0[1], p0[2], p0[3]};
    *reinterpret_cast<uint4*>(base + 8192) = (uint4){p1[0], p1[1], p1[2], p1[3]};
  };

  auto compute = [&](int cb_) {
#pragma unroll
    for (int ks = 0; ks < 2; ++ks) {
      const char* ab = afBase + cb_ * 16384 + s * 8192 + ks * 4096 + ih * 1024;
      sv8 a = *reinterpret_cast<const sv8*>(
          ab + (((q * 16 + lm) * 16) ^ (q << 4) ^ (ks << 6)));
#pragma unroll
      for (int n = 0; n < 5; ++n) {
        sv8 xb = *reinterpret_cast<const sv8*>(&Xf[cb_][ks * 5 + n][lane][0]);
        acc[n] = __builtin_amdgcn_mfma_f32_16x16x32_bf16(a, xb, acc[n], 0, 0, 0);
      }
    }
  };

  // ---- prologue: stage tile 0 ----
  dmaX(0, 0);
  loadA(0);
  asm volatile("s_waitcnt vmcnt(0)" ::: "memory");
  packWrite(0);
  asm volatile("s_waitcnt lgkmcnt(0)" ::: "memory");
  __builtin_amdgcn_s_barrier();
  __builtin_amdgcn_sched_barrier(0);

#pragma unroll 1
  for (int T = 0; T < 15; ++T) {
    const int nb = (T + 1) & 1;
    dmaX(nb, T + 1);
    loadA(T + 1);
    compute(T & 1);
    asm volatile("s_waitcnt vmcnt(0)" ::: "memory");
    packWrite(nb);
    asm volatile("s_waitcnt lgkmcnt(0)" ::: "memory");
    __builtin_amdgcn_s_barrier();
    __builtin_amdgcn_sched_barrier(0);
  }
  compute(1);  // tile 15
  __syncthreads();  // before LDS reuse

  // ---- epilogue: acc -> LDS bf16 [64][136] -> coalesced global ----
  u16* ep = (u16*)afBase;
#pragma unroll
  for (int n = 0; n < 5; ++n) {
    int f = n * 16 + lm;
    if (f < 66) {
#pragma unroll
      for (int r = 0; r < 4; ++r) {
        int row = ih * 16 + q * 4 + r;
        ep[row * 136 + s * 66 + f] = bf16bits(acc[n][r]);
      }
    }
  }
  __syncthreads();
  const u32* ep32 = reinterpret_cast<const u32*>(ep);  // [64][68]
  u32* og = reinterpret_cast<u32*>(xfeat) + ((size_t)b * kN + i0) * 66;
#pragma unroll 1
  for (int g = t; g < 4224; g += 512) {
    int row = g / 66, c = g - row * 66;
    og[g] = ep32[row * 68 + c];
  }
}

// ---------------------------------------------------------------------------
// K3: r/u gates (xfeat bf16).
// ---------------------------------------------------------------------------
__global__ __launch_bounds__(256) void gates_ru(
    const u16* __restrict__ xfeat, const float* __restrict__ rk,
    const float* __restrict__ rbias, const float* __restrict__ uk,
    const float* __restrict__ ubias, const float* __restrict__ inputs,
    const float* __restrict__ h_prev, float* __restrict__ u_buf,
    __hip_bfloat16* __restrict__ x0tc) {
  const int row0 = blockIdx.x * 32;
  const int b = row0 >> 10, n0 = row0 & 1023;
  const int t = threadIdx.x;
  __shared__ float xm[32][134];
  __shared__ float x0s[32][66];

  {
    const u32* xsrc = reinterpret_cast<const u32*>(xfeat) + (size_t)row0 * 66;
#pragma unroll 1
    for (int g = t; g < 2112; g += 256) {
      int row = g / 66, c = g - row * 66;
      u32 v = xsrc[g];
      xm[row][c * 2]     = bflo(v);
      xm[row][c * 2 + 1] = bfhi(v);
    }
  }
#pragma unroll
  for (int r2 = 0; r2 < 8; ++r2) {
    int idx = t + (r2 << 8);
    int rw = idx >> 6, u = idx & 63;
    x0s[rw][2 + u] = h_prev[(size_t)(row0 + rw) * kU + u];
  }
  if (t < 64) x0s[t >> 1][t & 1] = inputs[(size_t)row0 * 2 + t];
  __syncthreads();

  const int cu = t & 15;
  const int rw = (t >> 4) * 2;
  float ar[2][4] = {{0.f,0.f,0.f,0.f},{0.f,0.f,0.f,0.f}};
  float au[2][4] = {{0.f,0.f,0.f,0.f},{0.f,0.f,0.f,0.f}};

#pragma unroll 4
  for (int f = 0; f < 66; ++f) {  // m = 0
    float4 vr = *reinterpret_cast<const float4*>(rk + (size_t)(f * 3) * kU + cu * 4);
    float4 vu = *reinterpret_cast<const float4*>(uk + (size_t)(f * 3) * kU + cu * 4);
    float a0 = x0s[rw][f], a1 = x0s[rw + 1][f];
    ar[0][0] += a0 * vr.x; ar[0][1] += a0 * vr.y; ar[0][2] += a0 * vr.z; ar[0][3] += a0 * vr.w;
    ar[1][0] += a1 * vr.x; ar[1][1] += a1 * vr.y; ar[1][2] += a1 * vr.z; ar[1][3] += a1 * vr.w;
    au[0][0] += a0 * vu.x; au[0][1] += a0 * vu.y; au[0][2] += a0 * vu.z; au[0][3] += a0 * vu.w;
    au[1][0] += a1 * vu.x; au[1][1] += a1 * vu.y; au[1][2] += a1 * vu.z; au[1][3] += a1 * vu.w;
  }
#pragma unroll
  for (int m = 1; m <= 2; ++m) {
#pragma unroll 4
    for (int f = 0; f < 66; ++f) {
      float4 vr = *reinterpret_cast<const float4*>(rk + (size_t)(f * 3 + m) * kU + cu * 4);
      float4 vu = *reinterpret_cast<const float4*>(uk + (size_t)(f * 3 + m) * kU + cu * 4);
      float a0 = xm[rw][(m - 1) * 66 + f], a1 = xm[rw + 1][(m - 1) * 66 + f];
      ar[0][0] += a0 * vr.x; ar[0][1] += a0 * vr.y; ar[0][2] += a0 * vr.z; ar[0][3] += a0 * vr.w;
      ar[1][0] += a1 * vr.x; ar[1][1] += a1 * vr.y; ar[1][2] += a1 * vr.z; ar[1][3] += a1 * vr.w;
      au[0][0] += a0 * vu.x; au[0][1] += a0 * vu.y; au[0][2] += a0 * vu.z; au[0][3] += a0 * vu.w;
      au[1][0] += a1 * vu.x; au[1][1] += a1 * vu.y; au[1][2] += a1 * vu.z; au[1][3] += a1 * vu.w;
    }
  }

#pragma unroll
  for (int rr = 0; rr < 2; ++rr) {
    int grow = row0 + rw + rr;
    int n = n0 + rw + rr;
#pragma unroll
    for (int j = 0; j < 4; ++j) {
      int u = cu * 4 + j;
      float rv = 1.f / (1.f + __expf(-(ar[rr][j] + rbias[u])));
      float uv = 1.f / (1.f + __expf(-(au[rr][j] + ubias[u])));
      u_buf[(size_t)grow * kU + u] = uv;
      float rh = rv * h_prev[(size_t)grow * kU + u];
      x0tc[((size_t)b * kFP + 2 + u) * kN + n] = __float2bfloat16(rh);
    }
  }
}

// ---------------------------------------------------------------------------
// K5: c gate + GRU update (xfeat bf16).
// ---------------------------------------------------------------------------
__global__ __launch_bounds__(256) void gate_c_final(
    const u16* __restrict__ xfeat, const float* __restrict__ ck,
    const float* __restrict__ cbias, const float* __restrict__ inputs,
    const __hip_bfloat16* __restrict__ x0tc, const float* __restrict__ h_prev,
    const float* __restrict__ u_buf, float* __restrict__ out) {
  const int row0 = blockIdx.x * 32;
  const int b = row0 >> 10, n0 = row0 & 1023;
  const int t = threadIdx.x;
  __shared__ float xm[32][134];
  __shared__ float x0c[32][66];

  {
    const u32* xsrc = reinterpret_cast<const u32*>(xfeat) + (size_t)row0 * 66;
#pragma unroll 1
    for (int g = t; g < 2112; g += 256) {
      int row = g / 66, c = g - row * 66;
      u32 v = xsrc[g];
      xm[row][c * 2]     = bflo(v);
      xm[row][c * 2 + 1] = bfhi(v);
    }
  }
#pragma unroll
  for (int r2 = 0; r2 < 8; ++r2) {
    int idx = t + (r2 << 8);
    int u = idx >> 5, nn = idx & 31;
    x0c[nn][2 + u] =
        __bfloat162float(x0tc[((size_t)b * kFP + 2 + u) * kN + n0 + nn]);
  }
  if (t < 64) x0c[t >> 1][t & 1] = inputs[(size_t)row0 * 2 + t];
  __syncthreads();

  const int cu = t & 15;
  const int rw = (t >> 4) * 2;
  float ac[2][4] = {{0.f,0.f,0.f,0.f},{0.f,0.f,0.f,0.f}};

#pragma unroll 4
  for (int f = 0; f < 66; ++f) {  // m = 0
    float4 vc = *reinterpret_cast<const float4*>(ck + (size_t)(f * 3) * kU + cu * 4);
    float a0 = x0c[rw][f], a1 = x0c[rw + 1][f];
    ac[0][0] += a0 * vc.x; ac[0][1] += a0 * vc.y; ac[0][2] += a0 * vc.z; ac[0][3] += a0 * vc.w;
    ac[1][0] += a1 * vc.x; ac[1][1] += a1 * vc.y; ac[1][2] += a1 * vc.z; ac[1][3] += a1 * vc.w;
  }
#pragma unroll
  for (int m = 1; m <= 2; ++m) {
#pragma unroll 4
    for (int f = 0; f < 66; ++f) {
      float4 vc = *reinterpret_cast<const float4*>(ck + (size_t)(f * 3 + m) * kU + cu * 4);
      float a0 = xm[rw][(m - 1) * 66 + f], a1 = xm[rw + 1][(m - 1) * 66 + f];
      ac[0][0] += a0 * vc.x; ac[0][1] += a0 * vc.y; ac[0][2] += a0 * vc.z; ac[0][3] += a0 * vc.w;
      ac[1][0] += a1 * vc.x; ac[1][1] += a1 * vc.y; ac[1][2] += a1 * vc.z; ac[1][3] += a1 * vc.w;
    }
  }

#pragma unroll
  for (int rr = 0; rr < 2; ++rr) {
    int grow = row0 + rw + rr;
#pragma unroll
    for (int j = 0; j < 4; ++j) {
      int u = cu * 4 + j;
      float cv = tanhf(ac[rr][j] + cbias[u]);
      float uv = u_buf[(size_t)grow * kU + u];
      float hp = h_prev[(size_t)grow * kU + u];
      out[(size_t)grow * kU + u] = uv * hp + (1.f - uv) * cv;
    }
  }
}

}  // namespace

extern "C" void kernel_launch(void* const* d_in, const int* in_sizes, int n_in,
                              void* d_out, int out_size, void* d_ws, size_t ws_size,
                              hipStream_t stream) {
  const float* inputs = (const float*)d_in[0];
  const float* sup    = (const float*)d_in[1];
  const float* h_prev = (const float*)d_in[2];
  const float* rk     = (const float*)d_in[3];
  const float* rbias  = (const float*)d_in[4];
  const float* uk     = (const float*)d_in[5];
  const float* ubias  = (const float*)d_in[6];
  const float* ck     = (const float*)d_in[7];
  const float* cbias  = (const float*)d_in[8];
  float* out = (float*)d_out;

  char* ws = (char*)d_ws;
  __hip_bfloat16* x0t   = (__hip_bfloat16*)(ws);                    //  5,242,880 B
  __hip_bfloat16* x0tc  = (__hip_bfloat16*)(ws + 5242880);          //  5,242,880 B
  u16*            xfeat = (u16*)(ws + 10485760);                    //  8,650,752 B
  float*          u_buf = (float*)(ws + 19136512);                  //  8,388,608 B
  u32*            supb  = (u32*)(ws + 27525120);                    // 134,217,728 B

  hipLaunchKernelGGL(convert_sup, dim3(4096), dim3(256), 0, stream,
                     (const f32x4*)sup, (uint2*)supb);
  hipLaunchKernelGGL(build_x0t, dim3(512), dim3(256), 0, stream,
                     inputs, h_prev, x0t, x0tc);
  hipLaunchKernelGGL(einsum_diff, dim3(512), dim3(512), 0, stream,
                     supb, x0t, xfeat);
  hipLaunchKernelGGL(gates_ru, dim3(1024), dim3(256), 0, stream,
                     xfeat, rk, rbias, uk, ubias, inputs, h_prev, u_buf, x0tc);
  hipLaunchKernelGGL(einsum_diff, dim3(512), dim3(512), 0, stream,
                     supb, x0tc, xfeat);
  hipLaunchKernelGGL(gate_c_final, dim3(1024), dim3(256), 0, stream,
                     xfeat, ck, cbias, inputs, x0tc, h_prev, u_buf, out);
}

// Round 9
// 212.256 us; speedup vs baseline: 1.2550x; 1.0519x over previous
//
#include <hip/hip_runtime.h>
#include <hip/hip_bf16.h>

namespace {

constexpr int kN  = 1024;
constexpr int kU  = 64;
constexpr int kFP = 80;   // padded feature dim (5 tiles of 16)

typedef __attribute__((ext_vector_type(4))) float f32x4;
typedef __attribute__((ext_vector_type(8))) short sv8;
typedef unsigned int u32;
typedef unsigned short u16;

__device__ __forceinline__ u32 pack_bf2(float a, float b) {
  __hip_bfloat16 ha = __float2bfloat16(a);
  __hip_bfloat16 hb = __float2bfloat16(b);
  u16 ua = *reinterpret_cast<u16*>(&ha);
  u16 ub = *reinterpret_cast<u16*>(&hb);
  return (u32)ua | ((u32)ub << 16);
}

__device__ __forceinline__ u16 bf16bits(float a) {
  __hip_bfloat16 h = __float2bfloat16(a);
  return *reinterpret_cast<u16*>(&h);
}

__device__ __forceinline__ float bflo(u32 v) {
  u32 x = v << 16;
  return *reinterpret_cast<float*>(&x);
}
__device__ __forceinline__ float bfhi(u32 v) {
  u32 x = v & 0xffff0000u;
  return *reinterpret_cast<float*>(&x);
}

__device__ __forceinline__ void gl16(const void* g, void* l) {
  __builtin_amdgcn_global_load_lds(
      (const __attribute__((address_space(1))) u32*)g,
      (__attribute__((address_space(3))) u32*)l, 16, 0, 0);
}

// ---------------------------------------------------------------------------
// K0: supports f32 -> bf16 (s-interleaved), pure linear stream.
// ---------------------------------------------------------------------------
__global__ __launch_bounds__(256) void convert_sup(
    const f32x4* __restrict__ sup4, uint2* __restrict__ outb) {
  const size_t n4 = (size_t)16 * 1024 * 1024;  // 64M floats / 4
  size_t idx = (size_t)blockIdx.x * 256 + threadIdx.x;
  const size_t stride = (size_t)gridDim.x * 256;
#pragma unroll 1
  for (; idx < n4; idx += stride) {
    f32x4 v = __builtin_nontemporal_load(sup4 + idx);
    uint2 o;
    o.x = pack_bf2(v[0], v[1]);
    o.y = pack_bf2(v[2], v[3]);
    outb[idx] = o;
  }
}

// ---------------------------------------------------------------------------
// K1: build x0^T bf16 (B, 80, 1024).
// ---------------------------------------------------------------------------
__global__ __launch_bounds__(256) void build_x0t(
    const float* __restrict__ inputs, const float* __restrict__ h_prev,
    __hip_bfloat16* __restrict__ x0t, __hip_bfloat16* __restrict__ x0tc) {
  const int bx = blockIdx.x;
  const int b  = bx >> 4;
  const int n0 = (bx & 15) * 64;
  const int t  = threadIdx.x;

  __shared__ float hp[64][65];

  const float* hpg = h_prev + (size_t)b * kN * kU + (size_t)n0 * kU;
#pragma unroll
  for (int r = 0; r < 16; ++r) {
    int idx = t + (r << 8);
    hp[idx >> 6][idx & 63] = hpg[idx];
  }
  __syncthreads();

  {
    int u = t >> 2, g = t & 3;
    __hip_bfloat16* dst = x0t + ((size_t)b * kFP + 2 + u) * kN + n0 + g * 16;
#pragma unroll
    for (int k = 0; k < 16; ++k) dst[k] = __float2bfloat16(hp[g * 16 + k][u]);
  }

  if (t < 128) {
    int d = t & 1, nn = t >> 1;
    float v = inputs[((size_t)b * kN + n0 + nn) * 2 + d];
    __hip_bfloat16 bv = __float2bfloat16(v);
    x0t [((size_t)b * kFP + d) * kN + n0 + nn] = bv;
    x0tc[((size_t)b * kFP + d) * kN + n0 + nn] = bv;
  } else {
    int i2 = t - 128;
    __hip_bfloat16 z = __float2bfloat16(0.0f);
#pragma unroll
    for (int r = 0; r < 7; ++r) {
      int idx = i2 + r * 128;
      int row = 66 + (idx >> 6), nn = idx & 63;
      x0t [((size_t)b * kFP + row) * kN + n0 + nn] = z;
      x0tc[((size_t)b * kFP + row) * kN + n0 + nn] = z;
    }
  }
}

// ---------------------------------------------------------------------------
// K2/K4: graph-diffusion einsum, bf16 MFMA. Depth-2 prefetch, triple-buffered
// LDS, counted vmcnt mid-loop. RACE-SAFE ordering: compute(T) sits BEFORE the
// end-of-step barrier, so the next step's DMA write to buf T%3 (issued only
// after all waves pass that barrier) cannot collide with compute(T)'s reads.
// ---------------------------------------------------------------------------
__global__ __launch_bounds__(512, 4) void einsum_diff(
    const u32* __restrict__ supb, const __hip_bfloat16* __restrict__ x0t,
    u16* __restrict__ xfeat) {
  const int bx = blockIdx.x;
  const int wk = (bx & 7) * 64 + (bx >> 3);  // XCD-chunked (512 = 8*64)
  const int b  = wk >> 4;
  const int i0 = (wk & 15) << 6;
  const int t    = threadIdx.x;
  const int lane = t & 63;
  const int w    = t >> 6;       // 0..7
  const int q    = lane >> 4;
  const int lm   = lane & 15;
  const int s    = w & 1;
  const int ih   = w >> 1;       // 0..3

  __shared__ u16 Af[3][8192];        // 3 x 16 KB  [s(8K)][ks(4K)][ihh(1K)][slot][8]
  __shared__ u16 Xf[3][10][64][8];   // 3 x 10 KB

  f32x4 acc[5];
#pragma unroll
  for (int n = 0; n < 5; ++n) acc[n] = (f32x4){0.f, 0.f, 0.f, 0.f};

  const u32* sb = supb + ((size_t)b * kN + i0) * kN;
  const u16* xg = reinterpret_cast<const u16*>(x0t) + (size_t)b * kFP * kN;

  // ---- A staging unit: thread -> (row ii, j8-group jb), 32 B contiguous ----
  const int ii = t >> 3, jb = t & 7;
  const u32* aSrc = sb + (size_t)ii * kN + jb * 8;
  const int ksA = jb >> 2, q2 = jb & 3;
  const int ihhA = ii >> 4, lm2 = ii & 15;
  const int aOff = ksA * 4096 + ihhA * 1024 +
                   (((q2 * 16 + lm2) * 16) ^ (q2 << 4) ^ (ksA << 6));
  char* const afBase = (char*)&Af[0][0];

  // ---- X DMA sources (seg = ks*5+n); wave w -> seg w, (w<2) seg w+8 ----
  const int seg1 = w;
  const int seg2 = w + 8;
  const u16* xs1 =
      xg + (size_t)((seg1 % 5) * 16 + lm) * kN + (seg1 / 5) * 32 + q * 8;
  const u16* xs2 = (w < 2)
      ? xg + (size_t)((seg2 % 5) * 16 + lm) * kN + (seg2 / 5) * 32 + q * 8
      : nullptr;

  auto dmaX = [&](int nb, int T) {
    int jo = T * 64;
    gl16(xs1 + jo, &Xf[nb][seg1][0][0]);
    if (w < 2) gl16(xs2 + jo, &Xf[nb][seg2][0][0]);
  };

  uint4 WA[3], WB[3];  // literal-indexed only (SROA to regs)

  auto loadA = [&](uint4& A1, uint4& A2, int T) {
    const u32* p = aSrc + T * 64;
    A1 = *reinterpret_cast<const uint4*>(p);
    A2 = *reinterpret_cast<const uint4*>(p + 4);
  };

  auto packW = [&](const uint4& A1, const uint4& A2, int nb) {
    u32 p0[4], p1[4];
    p0[0] = (A1.x & 0xffffu) | (A1.y << 16);
    p0[1] = (A1.z & 0xffffu) | (A1.w << 16);
    p0[2] = (A2.x & 0xffffu) | (A2.y << 16);
    p0[3] = (A2.z & 0xffffu) | (A2.w << 16);
    p1[0] = (A1.x >> 16) | (A1.y & 0xffff0000u);
    p1[1] = (A1.z >> 16) | (A1.w & 0xffff0000u);
    p1[2] = (A2.x >> 16) | (A2.y & 0xffff0000u);
    p1[3] = (A2.z >> 16) | (A2.w & 0xffff0000u);
    char* base = afBase + nb * 16384 + aOff;
    *reinterpret_cast<uint4*>(base)        = (uint4){p0[0], p0[1], p0[2], p0[3]};
    *reinterpret_cast<uint4*>(base + 8192) = (uint4){p1[0], p1[1], p1[2], p1[3]};
  };

  auto compute = [&](int nb) {
#pragma unroll
    for (int ks = 0; ks < 2; ++ks) {
      const char* ab = afBase + nb * 16384 + s * 8192 + ks * 4096 + ih * 1024;
      sv8 a = *reinterpret_cast<const sv8*>(
          ab + (((q * 16 + lm) * 16) ^ (q << 4) ^ (ks << 6)));
#pragma unroll
      for (int n = 0; n < 5; ++n) {
        sv8 xb = *reinterpret_cast<const sv8*>(&Xf[nb][ks * 5 + n][lane][0]);
        acc[n] = __builtin_amdgcn_mfma_f32_16x16x32_bf16(a, xb, acc[n], 0, 0, 0);
      }
    }
  };

  // ---- prologue: batches 0 and 1 in flight; pack 0; make buf0 visible ----
  dmaX(0, 0); loadA(WA[0], WB[0], 0);
  dmaX(1, 1); loadA(WA[1], WB[1], 1);
  if (w < 2) { asm volatile("s_waitcnt vmcnt(4)" ::: "memory"); }
  else       { asm volatile("s_waitcnt vmcnt(3)" ::: "memory"); }
  packW(WA[0], WB[0], 0);
  asm volatile("s_waitcnt lgkmcnt(0)" ::: "memory");
  __builtin_amdgcn_s_barrier();
  __builtin_amdgcn_sched_barrier(0);

  // STEP(T): issue(T+2); vmcnt -> batch T+1 landed (T+2 in flight);
  //          packW(T+1); lgkm(0); compute(T); barrier.
#define STEP(T)                                                             \
  {                                                                         \
    if ((T) + 2 <= 15) {                                                    \
      dmaX(((T) + 2) % 3, (T) + 2);                                         \
      loadA(WA[((T) + 2) % 3], WB[((T) + 2) % 3], (T) + 2);                 \
      if (w < 2) { asm volatile("s_waitcnt vmcnt(4)" ::: "memory"); }       \
      else       { asm volatile("s_waitcnt vmcnt(3)" ::: "memory"); }       \
    } else if ((T) + 1 <= 15) {                                             \
      asm volatile("s_waitcnt vmcnt(0)" ::: "memory");                      \
    }                                                                       \
    if ((T) + 1 <= 15) {                                                    \
      packW(WA[((T) + 1) % 3], WB[((T) + 1) % 3], ((T) + 1) % 3);           \
      asm volatile("s_waitcnt lgkmcnt(0)" ::: "memory");                    \
    }                                                                       \
    __builtin_amdgcn_sched_barrier(0);                                      \
    compute((T) % 3);                                                       \
    __builtin_amdgcn_s_barrier();                                           \
    __builtin_amdgcn_sched_barrier(0);                                      \
  }

  STEP(0)  STEP(1)  STEP(2)  STEP(3)
  STEP(4)  STEP(5)  STEP(6)  STEP(7)
  STEP(8)  STEP(9)  STEP(10) STEP(11)
  STEP(12) STEP(13) STEP(14) STEP(15)
#undef STEP

  // ---- epilogue: acc -> LDS bf16 [64][136] -> coalesced global ----
  u16* ep = (u16*)afBase;
#pragma unroll
  for (int n = 0; n < 5; ++n) {
    int f = n * 16 + lm;
    if (f < 66) {
#pragma unroll
      for (int r = 0; r < 4; ++r) {
        int row = ih * 16 + q * 4 + r;
        ep[row * 136 + s * 66 + f] = bf16bits(acc[n][r]);
      }
    }
  }
  __syncthreads();
  const u32* ep32 = reinterpret_cast<const u32*>(ep);  // [64][68]
  u32* og = reinterpret_cast<u32*>(xfeat) + ((size_t)b * kN + i0) * 66;
#pragma unroll 1
  for (int g = t; g < 4224; g += 512) {
    int row = g / 66, c = g - row * 66;
    og[g] = ep32[row * 68 + c];
  }
}

// ---------------------------------------------------------------------------
// K3: r/u gates (xfeat bf16).
// ---------------------------------------------------------------------------
__global__ __launch_bounds__(256) void gates_ru(
    const u16* __restrict__ xfeat, const float* __restrict__ rk,
    const float* __restrict__ rbias, const float* __restrict__ uk,
    const float* __restrict__ ubias, const float* __restrict__ inputs,
    const float* __restrict__ h_prev, float* __restrict__ u_buf,
    __hip_bfloat16* __restrict__ x0tc) {
  const int row0 = blockIdx.x * 32;
  const int b = row0 >> 10, n0 = row0 & 1023;
  const int t = threadIdx.x;
  __shared__ float xm[32][134];
  __shared__ float x0s[32][66];

  {
    const u32* xsrc = reinterpret_cast<const u32*>(xfeat) + (size_t)row0 * 66;
#pragma unroll 1
    for (int g = t; g < 2112; g += 256) {
      int row = g / 66, c = g - row * 66;
      u32 v = xsrc[g];
      xm[row][c * 2]     = bflo(v);
      xm[row][c * 2 + 1] = bfhi(v);
    }
  }
#pragma unroll
  for (int r2 = 0; r2 < 8; ++r2) {
    int idx = t + (r2 << 8);
    int rw = idx >> 6, u = idx & 63;
    x0s[rw][2 + u] = h_prev[(size_t)(row0 + rw) * kU + u];
  }
  if (t < 64) x0s[t >> 1][t & 1] = inputs[(size_t)row0 * 2 + t];
  __syncthreads();

  const int cu = t & 15;
  const int rw = (t >> 4) * 2;
  float ar[2][4] = {{0.f,0.f,0.f,0.f},{0.f,0.f,0.f,0.f}};
  float au[2][4] = {{0.f,0.f,0.f,0.f},{0.f,0.f,0.f,0.f}};

#pragma unroll 4
  for (int f = 0; f < 66; ++f) {  // m = 0
    float4 vr = *reinterpret_cast<const float4*>(rk + (size_t)(f * 3) * kU + cu * 4);
    float4 vu = *reinterpret_cast<const float4*>(uk + (size_t)(f * 3) * kU + cu * 4);
    float a0 = x0s[rw][f], a1 = x0s[rw + 1][f];
    ar[0][0] += a0 * vr.x; ar[0][1] += a0 * vr.y; ar[0][2] += a0 * vr.z; ar[0][3] += a0 * vr.w;
    ar[1][0] += a1 * vr.x; ar[1][1] += a1 * vr.y; ar[1][2] += a1 * vr.z; ar[1][3] += a1 * vr.w;
    au[0][0] += a0 * vu.x; au[0][1] += a0 * vu.y; au[0][2] += a0 * vu.z; au[0][3] += a0 * vu.w;
    au[1][0] += a1 * vu.x; au[1][1] += a1 * vu.y; au[1][2] += a1 * vu.z; au[1][3] += a1 * vu.w;
  }
#pragma unroll
  for (int m = 1; m <= 2; ++m) {
#pragma unroll 4
    for (int f = 0; f < 66; ++f) {
      float4 vr = *reinterpret_cast<const float4*>(rk + (size_t)(f * 3 + m) * kU + cu * 4);
      float4 vu = *reinterpret_cast<const float4*>(uk + (size_t)(f * 3 + m) * kU + cu * 4);
      float a0 = xm[rw][(m - 1) * 66 + f], a1 = xm[rw + 1][(m - 1) * 66 + f];
      ar[0][0] += a0 * vr.x; ar[0][1] += a0 * vr.y; ar[0][2] += a0 * vr.z; ar[0][3] += a0 * vr.w;
      ar[1][0] += a1 * vr.x; ar[1][1] += a1 * vr.y; ar[1][2] += a1 * vr.z; ar[1][3] += a1 * vr.w;
      au[0][0] += a0 * vu.x; au[0][1] += a0 * vu.y; au[0][2] += a0 * vu.z; au[0][3] += a0 * vu.w;
      au[1][0] += a1 * vu.x; au[1][1] += a1 * vu.y; au[1][2] += a1 * vu.z; au[1][3] += a1 * vu.w;
    }
  }

#pragma unroll
  for (int rr = 0; rr < 2; ++rr) {
    int grow = row0 + rw + rr;
    int n = n0 + rw + rr;
#pragma unroll
    for (int j = 0; j < 4; ++j) {
      int u = cu * 4 + j;
      float rv = 1.f / (1.f + __expf(-(ar[rr][j] + rbias[u])));
      float uv = 1.f / (1.f + __expf(-(au[rr][j] + ubias[u])));
      u_buf[(size_t)grow * kU + u] = uv;
      float rh = rv * h_prev[(size_t)grow * kU + u];
      x0tc[((size_t)b * kFP + 2 + u) * kN + n] = __float2bfloat16(rh);
    }
  }
}

// ---------------------------------------------------------------------------
// K5: c gate + GRU update (xfeat bf16).
// ---------------------------------------------------------------------------
__global__ __launch_bounds__(256) void gate_c_final(
    const u16* __restrict__ xfeat, const float* __restrict__ ck,
    const float* __restrict__ cbias, const float* __restrict__ inputs,
    const __hip_bfloat16* __restrict__ x0tc, const float* __restrict__ h_prev,
    const float* __restrict__ u_buf, float* __restrict__ out) {
  const int row0 = blockIdx.x * 32;
  const int b = row0 >> 10, n0 = row0 & 1023;
  const int t = threadIdx.x;
  __shared__ float xm[32][134];
  __shared__ float x0c[32][66];

  {
    const u32* xsrc = reinterpret_cast<const u32*>(xfeat) + (size_t)row0 * 66;
#pragma unroll 1
    for (int g = t; g < 2112; g += 256) {
      int row = g / 66, c = g - row * 66;
      u32 v = xsrc[g];
      xm[row][c * 2]     = bflo(v);
      xm[row][c * 2 + 1] = bfhi(v);
    }
  }
#pragma unroll
  for (int r2 = 0; r2 < 8; ++r2) {
    int idx = t + (r2 << 8);
    int u = idx >> 5, nn = idx & 31;
    x0c[nn][2 + u] =
        __bfloat162float(x0tc[((size_t)b * kFP + 2 + u) * kN + n0 + nn]);
  }
  if (t < 64) x0c[t >> 1][t & 1] = inputs[(size_t)row0 * 2 + t];
  __syncthreads();

  const int cu = t & 15;
  const int rw = (t >> 4) * 2;
  float ac[2][4] = {{0.f,0.f,0.f,0.f},{0.f,0.f,0.f,0.f}};

#pragma unroll 4
  for (int f = 0; f < 66; ++f) {  // m = 0
    float4 vc = *reinterpret_cast<const float4*>(ck + (size_t)(f * 3) * kU + cu * 4);
    float a0 = x0c[rw][f], a1 = x0c[rw + 1][f];
    ac[0][0] += a0 * vc.x; ac[0][1] += a0 * vc.y; ac[0][2] += a0 * vc.z; ac[0][3] += a0 * vc.w;
    ac[1][0] += a1 * vc.x; ac[1][1] += a1 * vc.y; ac[1][2] += a1 * vc.z; ac[1][3] += a1 * vc.w;
  }
#pragma unroll
  for (int m = 1; m <= 2; ++m) {
#pragma unroll 4
    for (int f = 0; f < 66; ++f) {
      float4 vc = *reinterpret_cast<const float4*>(ck + (size_t)(f * 3 + m) * kU + cu * 4);
      float a0 = xm[rw][(m - 1) * 66 + f], a1 = xm[rw + 1][(m - 1) * 66 + f];
      ac[0][0] += a0 * vc.x; ac[0][1] += a0 * vc.y; ac[0][2] += a0 * vc.z; ac[0][3] += a0 * vc.w;
      ac[1][0] += a1 * vc.x; ac[1][1] += a1 * vc.y; ac[1][2] += a1 * vc.z; ac[1][3] += a1 * vc.w;
    }
  }

#pragma unroll
  for (int rr = 0; rr < 2; ++rr) {
    int grow = row0 + rw + rr;
#pragma unroll
    for (int j = 0; j < 4; ++j) {
      int u = cu * 4 + j;
      float cv = tanhf(ac[rr][j] + cbias[u]);
      float uv = u_buf[(size_t)grow * kU + u];
      float hp = h_prev[(size_t)grow * kU + u];
      out[(size_t)grow * kU + u] = uv * hp + (1.f - uv) * cv;
    }
  }
}

}  // namespace

extern "C" void kernel_launch(void* const* d_in, const int* in_sizes, int n_in,
                              void* d_out, int out_size, void* d_ws, size_t ws_size,
                              hipStream_t stream) {
  const float* inputs = (const float*)d_in[0];
  const float* sup    = (const float*)d_in[1];
  const float* h_prev = (const float*)d_in[2];
  const float* rk     = (const float*)d_in[3];
  const float* rbias  = (const float*)d_in[4];
  const float* uk     = (const float*)d_in[5];
  const float* ubias  = (const float*)d_in[6];
  const float* ck     = (const float*)d_in[7];
  const float* cbias  = (const float*)d_in[8];
  float* out = (float*)d_out;

  char* ws = (char*)d_ws;
  __hip_bfloat16* x0t   = (__hip_bfloat16*)(ws);                    //  5,242,880 B
  __hip_bfloat16* x0tc  = (__hip_bfloat16*)(ws + 5242880);          //  5,242,880 B
  u16*            xfeat = (u16*)(ws + 10485760);                    //  8,650,752 B
  float*          u_buf = (float*)(ws + 19136512);                  //  8,388,608 B
  u32*            supb  = (u32*)(ws + 27525120);                    // 134,217,728 B

  hipLaunchKernelGGL(convert_sup, dim3(4096), dim3(256), 0, stream,
                     (const f32x4*)sup, (uint2*)supb);
  hipLaunchKernelGGL(build_x0t, dim3(512), dim3(256), 0, stream,
                     inputs, h_prev, x0t, x0tc);
  hipLaunchKernelGGL(einsum_diff, dim3(512), dim3(512), 0, stream,
                     supb, x0t, xfeat);
  hipLaunchKernelGGL(gates_ru, dim3(1024), dim3(256), 0, stream,
                     xfeat, rk, rbias, uk, ubias, inputs, h_prev, u_buf, x0tc);
  hipLaunchKernelGGL(einsum_diff, dim3(512), dim3(512), 0, stream,
                     supb, x0tc, xfeat);
  hipLaunchKernelGGL(gate_c_final, dim3(1024), dim3(256), 0, stream,
                     xfeat, ck, cbias, inputs, x0tc, h_prev, u_buf, out);
}